// Round 13
// baseline (205.963 us; speedup 1.0000x reference)
//
#include <hip/hip_runtime.h>
#include <hip/hip_fp16.h>

// ---------------------------------------------------------------------------
// GCN layer: out[b][f][t][n] = relu( rsqrt(deg_in[n]) *
//     sum_{e: dst[e]=n} ( rsqrt(deg_out[src[e]]) * x[src[e]] @ W )[b][t][f] + bias[f] )
// Strategy: (1) degrees+CSR, (2) GEMV-style transform -> y[n][512] fp16 plain
//           node-major, (3) CSR gather-sum + epilogue + transpose-back.
// R13: transform computes ALL 64 f per thread (acc[64]) with
//      __launch_bounds__(256,2) to uncap VGPRs (R2/R6/R8 "spills" were the
//      8-wave 64-VGPR cap, not true pressure). One x pass (z=1): 1 load+64 FMA
//      per h-step, W s_loads halved, 512-cycle prefetch window.
//      Aggregate reverted to R9 body (2x8B loads, unroll 4 — measured best).
// ---------------------------------------------------------------------------

extern "C" __global__ void k_deg(const int* __restrict__ src, const int* __restrict__ dst,
                                 int* __restrict__ deg_out, int* __restrict__ deg_in, int E) {
  int e = blockIdx.x * blockDim.x + threadIdx.x;
  if (e < E) {
    atomicAdd(&deg_out[src[e]], 1);
    atomicAdd(&deg_in[dst[e]], 1);
  }
}

// scan1 + rsqrt fused: block sums of deg_in, plus rs arrays.
extern "C" __global__ __launch_bounds__(256) void k_scan1(const int* __restrict__ deg_in,
                                                          const int* __restrict__ deg_out,
                                                          int* __restrict__ bsum,
                                                          float* __restrict__ rs_out,
                                                          float* __restrict__ rs_in, int N) {
  __shared__ int red[256];
  int tid = threadIdx.x;
  int i = blockIdx.x * 256 + tid;
  int di = (i < N) ? deg_in[i] : 0;
  red[tid] = di;
  if (i < N) {
    int a = deg_out[i] > 1 ? deg_out[i] : 1;
    int b = di > 1 ? di : 1;
    rs_out[i] = rsqrtf((float)a);
    rs_in[i]  = rsqrtf((float)b);
  }
  __syncthreads();
  #pragma unroll
  for (int off = 128; off > 0; off >>= 1) {
    if (tid < off) red[tid] += red[tid + off];
    __syncthreads();
  }
  if (tid == 0) bsum[blockIdx.x] = red[0];
}

extern "C" __global__ __launch_bounds__(256) void k_scan2(const int* __restrict__ bsum,
                                                          int* __restrict__ boffs,
                                                          int* __restrict__ offs, int M, int N) {
  __shared__ int sc[256];
  int tid = threadIdx.x;
  int v = (tid < M) ? bsum[tid] : 0;
  sc[tid] = v;
  __syncthreads();
  #pragma unroll
  for (int off = 1; off < 256; off <<= 1) {
    int t = sc[tid];
    if (tid >= off) t += sc[tid - off];
    __syncthreads();
    sc[tid] = t;
    __syncthreads();
  }
  boffs[tid] = sc[tid] - v;           // exclusive block offset
  if (tid == 255) offs[N] = sc[255];  // total edge count
}

extern "C" __global__ __launch_bounds__(256) void k_scan3(const int* __restrict__ deg,
                                                          const int* __restrict__ boffs,
                                                          int* __restrict__ offs, int N) {
  __shared__ int sc[256];
  int tid = threadIdx.x;
  int i = blockIdx.x * 256 + tid;
  int v = (i < N) ? deg[i] : 0;
  sc[tid] = v;
  __syncthreads();
  #pragma unroll
  for (int off = 1; off < 256; off <<= 1) {
    int t = sc[tid];
    if (tid >= off) t += sc[tid - off];
    __syncthreads();
    sc[tid] = t;
    __syncthreads();
  }
  if (i < N) offs[i] = boffs[blockIdx.x] + sc[tid] - v;
}

extern "C" __global__ void k_scatter(const int* __restrict__ src, const int* __restrict__ dst,
                                     const int* __restrict__ offs, int* __restrict__ cursor,
                                     int* __restrict__ csr_src, int E) {
  int e = blockIdx.x * blockDim.x + threadIdx.x;
  if (e < E) {
    int d = dst[e];
    int pos = offs[d] + atomicAdd(&cursor[d], 1);
    csr_src[pos] = src[e];
  }
}

// Transform: wave = 64 nodes (lane = node) x one bt x ALL 64 f's.
// __launch_bounds__(256,2) uncaps VGPR (acc[64]+prefetch ~90 VGPR, ~5
// waves/SIMD). Cross-iteration prefetch (R9). Per h-step: 1 coalesced load +
// 64 FMA with wave-uniform W scalar operands. One x pass total.
extern "C" __global__ __launch_bounds__(256, 2) void k_transform(
    const float* __restrict__ in_feat, const float* __restrict__ W,
    const float* __restrict__ rs_out, __half* __restrict__ y, int N) {
  int tid = threadIdx.x;
  int wave = tid >> 6, lane = tid & 63;
  int bt = blockIdx.y * 4 + wave;     // 0..7
  int b = bt >> 2, t = bt & 3;
  int n = blockIdx.x * 64 + lane;

  const float* xp = in_feat + (size_t)(b * 256 + t) * (size_t)N;  // h=0 row
  size_t hstride = (size_t)4 * (size_t)N;

  float acc[64];
  #pragma unroll
  for (int f = 0; f < 64; ++f) acc[f] = 0.0f;

  bool ok = (n < N);

  float xcur[4], xnxt[4];
  #pragma unroll
  for (int u = 0; u < 4; ++u)
    xcur[u] = ok ? xp[(size_t)u * hstride + n] : 0.0f;

  #pragma unroll 1
  for (int h0 = 0; h0 < 60; h0 += 4) {
    #pragma unroll
    for (int u = 0; u < 4; ++u)
      xnxt[u] = ok ? xp[(size_t)(h0 + 4 + u) * hstride + n] : 0.0f;
    #pragma unroll
    for (int u = 0; u < 4; ++u) {
      const float* wrow = W + (h0 + u) * 64;   // wave-uniform -> s_load
      #pragma unroll
      for (int f = 0; f < 64; ++f) acc[f] = fmaf(xcur[u], wrow[f], acc[f]);
    }
    #pragma unroll
    for (int u = 0; u < 4; ++u) xcur[u] = xnxt[u];
  }
  #pragma unroll
  for (int u = 0; u < 4; ++u) {
    const float* wrow = W + (60 + u) * 64;
    #pragma unroll
    for (int f = 0; f < 64; ++f) acc[f] = fmaf(xcur[u], wrow[f], acc[f]);
  }

  if (ok) {
    float rs = rs_out[n];
    union { unsigned int u[32]; uint4 v[8]; } pk;
    #pragma unroll
    for (int q = 0; q < 32; ++q) {
      __half2 h2 = __float22half2_rn(make_float2(acc[2 * q] * rs, acc[2 * q + 1] * rs));
      pk.u[q] = *(unsigned int*)&h2;
    }
    uint4* yp = (uint4*)(y + (size_t)n * 512 + bt * 64);
    #pragma unroll
    for (int q = 0; q < 8; ++q) yp[q] = pk.v[q];
  }
}

// Aggregate (R9 body — measured best): 512 threads = 8 waves; wave handles 2
// nodes (16-node tile, 33KB LDS -> 4 blocks/CU -> 32 waves/CU). Per edge:
// 2x8B loads (channels 4l..4l+3 and 256+4l..+3), unroll 4.
extern "C" __global__ __launch_bounds__(512) void k_aggregate(
    const __half* __restrict__ y, const int* __restrict__ offs,
    const int* __restrict__ csr_src, const float* __restrict__ rs_in,
    const float* __restrict__ bvec, float* __restrict__ out, int N) {
  __shared__ float agg[16 * 513];
  int tid = threadIdx.x;
  int lane = tid & 63, wave = tid >> 6;   // 8 waves
  int n0 = blockIdx.x * 16;

#define ACC_EDGE(s)                                                          \
  {                                                                          \
    const uint2* rp = (const uint2*)(y + (size_t)(s) * 512);                 \
    uint2 ua = rp[lane];                                                     \
    uint2 ub = rp[64 + lane];                                                \
    float2 f;                                                                \
    f = __half22float2(*(const __half2*)&ua.x); accA.x += f.x; accA.y += f.y;\
    f = __half22float2(*(const __half2*)&ua.y); accA.z += f.x; accA.w += f.y;\
    f = __half22float2(*(const __half2*)&ub.x); accB.x += f.x; accB.y += f.y;\
    f = __half22float2(*(const __half2*)&ub.y); accB.z += f.x; accB.w += f.y;\
  }

  #pragma unroll
  for (int k = 0; k < 2; ++k) {
    int nl = k * 8 + wave;
    int n = n0 + nl;
    float4 accA = {0.f, 0.f, 0.f, 0.f};
    float4 accB = {0.f, 0.f, 0.f, 0.f};
    if (n < N) {
      int j0 = offs[n], j1 = offs[n + 1];
      for (int base = j0; base < j1; base += 64) {
        int idxv = csr_src[base + lane];  // coalesced block of up to 64 indices
        int m = j1 - base; if (m > 64) m = 64;
        int e = 0;
        for (; e + 3 < m; e += 4) {
          int s0 = __builtin_amdgcn_readlane(idxv, e);
          int s1 = __builtin_amdgcn_readlane(idxv, e + 1);
          int s2 = __builtin_amdgcn_readlane(idxv, e + 2);
          int s3 = __builtin_amdgcn_readlane(idxv, e + 3);
          ACC_EDGE(s0); ACC_EDGE(s1); ACC_EDGE(s2); ACC_EDGE(s3);
        }
        for (; e < m; ++e) {
          int s0 = __builtin_amdgcn_readlane(idxv, e);
          ACC_EDGE(s0);
        }
      }
    }
    *(float4*)&agg[nl * 513 + lane * 4] = accA;
    *(float4*)&agg[nl * 513 + 256 + lane * 4] = accB;
  }
#undef ACC_EDGE
  __syncthreads();

  // epilogue: scale, bias, relu, transpose-back to channel-major
  int nl = tid & 15;
  int r0 = tid >> 4;  // 0..31
  int n = n0 + nl;
  float rs = (n < N) ? rs_in[n] : 0.0f;
  #pragma unroll 4
  for (int it = 0; it < 16; ++it) {
    int c = it * 32 + r0;          // c = (b*4+t)*64 + f
    float v = agg[nl * 513 + c];
    int f = c & 63, bt = c >> 6;
    int b = bt >> 2, t = bt & 3;
    v = v * rs + bvec[f];
    v = fmaxf(v, 0.0f);
    if (n < N) out[(size_t)((b * 64 + f) * 4 + t) * (size_t)N + n] = v;
  }
}

extern "C" void kernel_launch(void* const* d_in, const int* in_sizes, int n_in,
                              void* d_out, int out_size, void* d_ws, size_t ws_size,
                              hipStream_t stream) {
  const float* in_feat = (const float*)d_in[0];
  const int*   src     = (const int*)d_in[1];
  const int*   dst     = (const int*)d_in[2];
  const float* W       = (const float*)d_in[3];
  const float* bvec    = (const float*)d_in[4];
  float* out = (float*)d_out;

  int N = in_sizes[0] / 512;   // B*H*T = 2*64*4 = 512
  int E = in_sizes[1];

  int A  = (N + 64) & ~63;     // room for N+1 offsets, 64-aligned
  int EA = (E + 63) & ~63;
  int M  = (N + 255) / 256;    // scan blocks (<= 256 for N <= 65536)

  // layout: the three arrays needing zero-init come first (one memset)
  int*   deg_out_i = (int*)d_ws;        // [A]  zeroed
  int*   deg_in_i  = deg_out_i + A;     // [A]  zeroed
  int*   cursor    = deg_in_i + A;      // [A]  zeroed
  int*   offs      = cursor + A;        // [A] (N+1 used, fully written by scans)
  int*   bsum      = offs + A;          // [256]
  int*   boffs     = bsum + 256;        // [256]
  float* rs_out    = (float*)(boffs + 256);
  float* rs_in     = rs_out + A;
  int*   csr_src   = (int*)(rs_in + A); // [EA] (+slack: y follows, overreads safe)
  __half* y        = (__half*)(csr_src + EA); // [N*512] fp16, plain layout

  hipMemsetAsync(deg_out_i, 0, (size_t)(3 * A) * sizeof(int), stream);
  hipLaunchKernelGGL(k_deg, dim3((E + 255) / 256), dim3(256), 0, stream,
                     src, dst, deg_out_i, deg_in_i, E);
  hipLaunchKernelGGL(k_scan1, dim3(M), dim3(256), 0, stream,
                     deg_in_i, deg_out_i, bsum, rs_out, rs_in, N);
  hipLaunchKernelGGL(k_scan2, dim3(1), dim3(256), 0, stream, bsum, boffs, offs, M, N);
  hipLaunchKernelGGL(k_scan3, dim3(M), dim3(256), 0, stream, deg_in_i, boffs, offs, N);
  hipLaunchKernelGGL(k_scatter, dim3((E + 255) / 256), dim3(256), 0, stream,
                     src, dst, offs, cursor, csr_src, E);
  hipLaunchKernelGGL(k_transform, dim3((N + 63) / 64, 2, 1), dim3(256), 0, stream,
                     in_feat, W, rs_out, y, N);
  hipLaunchKernelGGL(k_aggregate, dim3((N + 15) / 16), dim3(512), 0, stream,
                     y, offs, csr_src, rs_in, bvec, out, N);
}

// Round 14
// 199.258 us; speedup vs baseline: 1.0336x; 1.0336x over previous
//
#include <hip/hip_runtime.h>
#include <hip/hip_fp16.h>

// ---------------------------------------------------------------------------
// GCN layer: out[b][f][t][n] = relu( rsqrt(deg_in[n]) *
//     sum_{e: dst[e]=n} ( rsqrt(deg_out[src[e]]) * x[src[e]] @ W )[b][t][f] + bias[f] )
// Strategy: (1) degrees+CSR, (2) GEMV-style transform -> y[n][512] fp16 plain
//           node-major, (3) CSR gather-sum + epilogue + transpose-back.
// R14: consolidation. Transform = R12 known-good (f-split z=2, acc[32],
//      prefetch; R13's acc[64]+launch_bounds failed: allocator still caps).
//      Aggregate = R9 body (2x8B/edge) with edge unroll 8 (16 loads in
//      flight). W s_load serialization identified as transform's structural
//      stall (duty 64/(100+64) = 39% ~= measured VALUBusy) — future: MFMA.
// ---------------------------------------------------------------------------

extern "C" __global__ void k_deg(const int* __restrict__ src, const int* __restrict__ dst,
                                 int* __restrict__ deg_out, int* __restrict__ deg_in, int E) {
  int e = blockIdx.x * blockDim.x + threadIdx.x;
  if (e < E) {
    atomicAdd(&deg_out[src[e]], 1);
    atomicAdd(&deg_in[dst[e]], 1);
  }
}

// scan1 + rsqrt fused: block sums of deg_in, plus rs arrays.
extern "C" __global__ __launch_bounds__(256) void k_scan1(const int* __restrict__ deg_in,
                                                          const int* __restrict__ deg_out,
                                                          int* __restrict__ bsum,
                                                          float* __restrict__ rs_out,
                                                          float* __restrict__ rs_in, int N) {
  __shared__ int red[256];
  int tid = threadIdx.x;
  int i = blockIdx.x * 256 + tid;
  int di = (i < N) ? deg_in[i] : 0;
  red[tid] = di;
  if (i < N) {
    int a = deg_out[i] > 1 ? deg_out[i] : 1;
    int b = di > 1 ? di : 1;
    rs_out[i] = rsqrtf((float)a);
    rs_in[i]  = rsqrtf((float)b);
  }
  __syncthreads();
  #pragma unroll
  for (int off = 128; off > 0; off >>= 1) {
    if (tid < off) red[tid] += red[tid + off];
    __syncthreads();
  }
  if (tid == 0) bsum[blockIdx.x] = red[0];
}

extern "C" __global__ __launch_bounds__(256) void k_scan2(const int* __restrict__ bsum,
                                                          int* __restrict__ boffs,
                                                          int* __restrict__ offs, int M, int N) {
  __shared__ int sc[256];
  int tid = threadIdx.x;
  int v = (tid < M) ? bsum[tid] : 0;
  sc[tid] = v;
  __syncthreads();
  #pragma unroll
  for (int off = 1; off < 256; off <<= 1) {
    int t = sc[tid];
    if (tid >= off) t += sc[tid - off];
    __syncthreads();
    sc[tid] = t;
    __syncthreads();
  }
  boffs[tid] = sc[tid] - v;           // exclusive block offset
  if (tid == 255) offs[N] = sc[255];  // total edge count
}

extern "C" __global__ __launch_bounds__(256) void k_scan3(const int* __restrict__ deg,
                                                          const int* __restrict__ boffs,
                                                          int* __restrict__ offs, int N) {
  __shared__ int sc[256];
  int tid = threadIdx.x;
  int i = blockIdx.x * 256 + tid;
  int v = (i < N) ? deg[i] : 0;
  sc[tid] = v;
  __syncthreads();
  #pragma unroll
  for (int off = 1; off < 256; off <<= 1) {
    int t = sc[tid];
    if (tid >= off) t += sc[tid - off];
    __syncthreads();
    sc[tid] = t;
    __syncthreads();
  }
  if (i < N) offs[i] = boffs[blockIdx.x] + sc[tid] - v;
}

extern "C" __global__ void k_scatter(const int* __restrict__ src, const int* __restrict__ dst,
                                     const int* __restrict__ offs, int* __restrict__ cursor,
                                     int* __restrict__ csr_src, int E) {
  int e = blockIdx.x * blockDim.x + threadIdx.x;
  if (e < E) {
    int d = dst[e];
    int pos = offs[d] + atomicAdd(&cursor[d], 1);
    csr_src[pos] = src[e];
  }
}

// Transform (R12 known-good): wave = 64 nodes (lane = node) x one bt x 32 f's,
// cross-iteration prefetch, contiguous 64B/thread y stores. y PLAIN layout.
extern "C" __global__ __launch_bounds__(256) void k_transform(
    const float* __restrict__ in_feat, const float* __restrict__ W,
    const float* __restrict__ rs_out, __half* __restrict__ y, int N) {
  int tid = threadIdx.x;
  int wave = tid >> 6, lane = tid & 63;
  int bt = blockIdx.y * 4 + wave;     // 0..7
  int b = bt >> 2, t = bt & 3;
  int fh = blockIdx.z * 32;           // f half: 0 or 32
  int n = blockIdx.x * 64 + lane;

  const float* xp = in_feat + (size_t)(b * 256 + t) * (size_t)N;  // h=0 row
  size_t hstride = (size_t)4 * (size_t)N;

  float acc[32];
  #pragma unroll
  for (int f = 0; f < 32; ++f) acc[f] = 0.0f;

  bool ok = (n < N);

  float xcur[4], xnxt[4];
  #pragma unroll
  for (int u = 0; u < 4; ++u)
    xcur[u] = ok ? xp[(size_t)u * hstride + n] : 0.0f;

  #pragma unroll 1
  for (int h0 = 0; h0 < 60; h0 += 4) {
    #pragma unroll
    for (int u = 0; u < 4; ++u)
      xnxt[u] = ok ? xp[(size_t)(h0 + 4 + u) * hstride + n] : 0.0f;
    #pragma unroll
    for (int u = 0; u < 4; ++u) {
      const float* wrow = W + (h0 + u) * 64 + fh;   // uniform -> s_load
      #pragma unroll
      for (int f = 0; f < 32; ++f) acc[f] = fmaf(xcur[u], wrow[f], acc[f]);
    }
    #pragma unroll
    for (int u = 0; u < 4; ++u) xcur[u] = xnxt[u];
  }
  #pragma unroll
  for (int u = 0; u < 4; ++u) {
    const float* wrow = W + (60 + u) * 64 + fh;
    #pragma unroll
    for (int f = 0; f < 32; ++f) acc[f] = fmaf(xcur[u], wrow[f], acc[f]);
  }

  if (ok) {
    float rs = rs_out[n];
    union { unsigned int u[16]; uint4 v[4]; } pk;
    #pragma unroll
    for (int q = 0; q < 16; ++q) {
      __half2 h2 = __float22half2_rn(make_float2(acc[2 * q] * rs, acc[2 * q + 1] * rs));
      pk.u[q] = *(unsigned int*)&h2;
    }
    uint4* yp = (uint4*)(y + (size_t)n * 512 + bt * 64 + fh);
    #pragma unroll
    for (int q = 0; q < 4; ++q) yp[q] = pk.v[q];
  }
}

// Aggregate: R9 body with edge unroll 8. 512 threads = 8 waves; wave handles
// 2 nodes (16-node tile, 33KB LDS -> 4 blocks/CU -> 32 waves/CU). Per edge:
// 2x8B loads (channels 4l..4l+3 and 256+4l..+3); unroll 8 = 16 loads in
// flight per wave.
extern "C" __global__ __launch_bounds__(512) void k_aggregate(
    const __half* __restrict__ y, const int* __restrict__ offs,
    const int* __restrict__ csr_src, const float* __restrict__ rs_in,
    const float* __restrict__ bvec, float* __restrict__ out, int N) {
  __shared__ float agg[16 * 513];
  int tid = threadIdx.x;
  int lane = tid & 63, wave = tid >> 6;   // 8 waves
  int n0 = blockIdx.x * 16;

#define LDE(i, s)                                                            \
  const uint2* rp##i = (const uint2*)(y + (size_t)(s) * 512);                \
  uint2 ua##i = rp##i[lane];                                                 \
  uint2 ub##i = rp##i[64 + lane];
#define ADE(i)                                                               \
  {                                                                          \
    float2 f;                                                                \
    f = __half22float2(*(const __half2*)&ua##i.x); accA.x += f.x; accA.y += f.y; \
    f = __half22float2(*(const __half2*)&ua##i.y); accA.z += f.x; accA.w += f.y; \
    f = __half22float2(*(const __half2*)&ub##i.x); accB.x += f.x; accB.y += f.y; \
    f = __half22float2(*(const __half2*)&ub##i.y); accB.z += f.x; accB.w += f.y; \
  }

  #pragma unroll
  for (int k = 0; k < 2; ++k) {
    int nl = k * 8 + wave;
    int n = n0 + nl;
    float4 accA = {0.f, 0.f, 0.f, 0.f};
    float4 accB = {0.f, 0.f, 0.f, 0.f};
    if (n < N) {
      int j0 = offs[n], j1 = offs[n + 1];
      for (int base = j0; base < j1; base += 64) {
        int idxv = csr_src[base + lane];  // coalesced block of up to 64 indices
        int m = j1 - base; if (m > 64) m = 64;
        int e = 0;
        for (; e + 7 < m; e += 8) {
          int s0 = __builtin_amdgcn_readlane(idxv, e);
          int s1 = __builtin_amdgcn_readlane(idxv, e + 1);
          int s2 = __builtin_amdgcn_readlane(idxv, e + 2);
          int s3 = __builtin_amdgcn_readlane(idxv, e + 3);
          int s4 = __builtin_amdgcn_readlane(idxv, e + 4);
          int s5 = __builtin_amdgcn_readlane(idxv, e + 5);
          int s6 = __builtin_amdgcn_readlane(idxv, e + 6);
          int s7 = __builtin_amdgcn_readlane(idxv, e + 7);
          LDE(0, s0); LDE(1, s1); LDE(2, s2); LDE(3, s3);
          LDE(4, s4); LDE(5, s5); LDE(6, s6); LDE(7, s7);
          ADE(0); ADE(1); ADE(2); ADE(3); ADE(4); ADE(5); ADE(6); ADE(7);
        }
        for (; e + 3 < m; e += 4) {
          int s0 = __builtin_amdgcn_readlane(idxv, e);
          int s1 = __builtin_amdgcn_readlane(idxv, e + 1);
          int s2 = __builtin_amdgcn_readlane(idxv, e + 2);
          int s3 = __builtin_amdgcn_readlane(idxv, e + 3);
          LDE(0, s0); LDE(1, s1); LDE(2, s2); LDE(3, s3);
          ADE(0); ADE(1); ADE(2); ADE(3);
        }
        for (; e < m; ++e) {
          int s0 = __builtin_amdgcn_readlane(idxv, e);
          LDE(0, s0); ADE(0);
        }
      }
    }
    *(float4*)&agg[nl * 513 + lane * 4] = accA;
    *(float4*)&agg[nl * 513 + 256 + lane * 4] = accB;
  }
#undef LDE
#undef ADE
  __syncthreads();

  // epilogue: scale, bias, relu, transpose-back to channel-major
  int nl = tid & 15;
  int r0 = tid >> 4;  // 0..31
  int n = n0 + nl;
  float rs = (n < N) ? rs_in[n] : 0.0f;
  #pragma unroll 4
  for (int it = 0; it < 16; ++it) {
    int c = it * 32 + r0;          // c = (b*4+t)*64 + f
    float v = agg[nl * 513 + c];
    int f = c & 63, bt = c >> 6;
    int b = bt >> 2, t = bt & 3;
    v = v * rs + bvec[f];
    v = fmaxf(v, 0.0f);
    if (n < N) out[(size_t)((b * 64 + f) * 4 + t) * (size_t)N + n] = v;
  }
}

extern "C" void kernel_launch(void* const* d_in, const int* in_sizes, int n_in,
                              void* d_out, int out_size, void* d_ws, size_t ws_size,
                              hipStream_t stream) {
  const float* in_feat = (const float*)d_in[0];
  const int*   src     = (const int*)d_in[1];
  const int*   dst     = (const int*)d_in[2];
  const float* W       = (const float*)d_in[3];
  const float* bvec    = (const float*)d_in[4];
  float* out = (float*)d_out;

  int N = in_sizes[0] / 512;   // B*H*T = 2*64*4 = 512
  int E = in_sizes[1];

  int A  = (N + 64) & ~63;     // room for N+1 offsets, 64-aligned
  int EA = (E + 63) & ~63;
  int M  = (N + 255) / 256;    // scan blocks (<= 256 for N <= 65536)

  // layout: the three arrays needing zero-init come first (one memset)
  int*   deg_out_i = (int*)d_ws;        // [A]  zeroed
  int*   deg_in_i  = deg_out_i + A;     // [A]  zeroed
  int*   cursor    = deg_in_i + A;      // [A]  zeroed
  int*   offs      = cursor + A;        // [A] (N+1 used, fully written by scans)
  int*   bsum      = offs + A;          // [256]
  int*   boffs     = bsum + 256;        // [256]
  float* rs_out    = (float*)(boffs + 256);
  float* rs_in     = rs_out + A;
  int*   csr_src   = (int*)(rs_in + A); // [EA] (+slack: y follows, overreads safe)
  __half* y        = (__half*)(csr_src + EA); // [N*512] fp16, plain layout

  hipMemsetAsync(deg_out_i, 0, (size_t)(3 * A) * sizeof(int), stream);
  hipLaunchKernelGGL(k_deg, dim3((E + 255) / 256), dim3(256), 0, stream,
                     src, dst, deg_out_i, deg_in_i, E);
  hipLaunchKernelGGL(k_scan1, dim3(M), dim3(256), 0, stream,
                     deg_in_i, deg_out_i, bsum, rs_out, rs_in, N);
  hipLaunchKernelGGL(k_scan2, dim3(1), dim3(256), 0, stream, bsum, boffs, offs, M, N);
  hipLaunchKernelGGL(k_scan3, dim3(M), dim3(256), 0, stream, deg_in_i, boffs, offs, N);
  hipLaunchKernelGGL(k_scatter, dim3((E + 255) / 256), dim3(256), 0, stream,
                     src, dst, offs, cursor, csr_src, E);
  hipLaunchKernelGGL(k_transform, dim3((N + 63) / 64, 2, 2), dim3(256), 0, stream,
                     in_feat, W, rs_out, y, N);
  hipLaunchKernelGGL(k_aggregate, dim3((N + 15) / 16), dim3(512), 0, stream,
                     y, offs, csr_src, rs_in, bvec, out, N);
}

// Round 15
// 184.057 us; speedup vs baseline: 1.1190x; 1.0826x over previous
//
#include <hip/hip_runtime.h>
#include <hip/hip_fp16.h>

// ---------------------------------------------------------------------------
// GCN layer: out[b][f][t][n] = relu( rsqrt(deg_in[n]) *
//     sum_{e: dst[e]=n} ( rsqrt(deg_out[src[e]]) * x[src[e]] @ W )[b][t][f] + bias[f] )
// Strategy: (1) degrees+CSR, (2) MFMA transform -> y[n][512] fp16 plain
//           node-major, (3) CSR gather-sum + epilogue + transpose-back.
// R15: transform rewritten on v_mfma_f32_16x16x32_f16. Block = 16 nodes x all
//      8 bt (4 waves x 2 bt); W fragments preloaded into VGPRs (kills the
//      W s_load serialization that pinned VALUBusy at ~37% for 4 rounds);
//      rs_out folded into A fragment; single x pass. Fragment mapping (m89/
//      m97-verified): A[l&15][(l>>4)*8+j], B[(l>>4)*8+j][l&15],
//      D[(l>>4)*4+r][l&15]. Aggregate = R9 exact body (73.4us best).
// ---------------------------------------------------------------------------

typedef _Float16 half8 __attribute__((ext_vector_type(8)));
typedef float f32x4 __attribute__((ext_vector_type(4)));

extern "C" __global__ void k_deg(const int* __restrict__ src, const int* __restrict__ dst,
                                 int* __restrict__ deg_out, int* __restrict__ deg_in, int E) {
  int e = blockIdx.x * blockDim.x + threadIdx.x;
  if (e < E) {
    atomicAdd(&deg_out[src[e]], 1);
    atomicAdd(&deg_in[dst[e]], 1);
  }
}

// scan1 + rsqrt fused: block sums of deg_in, plus rs arrays.
extern "C" __global__ __launch_bounds__(256) void k_scan1(const int* __restrict__ deg_in,
                                                          const int* __restrict__ deg_out,
                                                          int* __restrict__ bsum,
                                                          float* __restrict__ rs_out,
                                                          float* __restrict__ rs_in, int N) {
  __shared__ int red[256];
  int tid = threadIdx.x;
  int i = blockIdx.x * 256 + tid;
  int di = (i < N) ? deg_in[i] : 0;
  red[tid] = di;
  if (i < N) {
    int a = deg_out[i] > 1 ? deg_out[i] : 1;
    int b = di > 1 ? di : 1;
    rs_out[i] = rsqrtf((float)a);
    rs_in[i]  = rsqrtf((float)b);
  }
  __syncthreads();
  #pragma unroll
  for (int off = 128; off > 0; off >>= 1) {
    if (tid < off) red[tid] += red[tid + off];
    __syncthreads();
  }
  if (tid == 0) bsum[blockIdx.x] = red[0];
}

extern "C" __global__ __launch_bounds__(256) void k_scan2(const int* __restrict__ bsum,
                                                          int* __restrict__ boffs,
                                                          int* __restrict__ offs, int M, int N) {
  __shared__ int sc[256];
  int tid = threadIdx.x;
  int v = (tid < M) ? bsum[tid] : 0;
  sc[tid] = v;
  __syncthreads();
  #pragma unroll
  for (int off = 1; off < 256; off <<= 1) {
    int t = sc[tid];
    if (tid >= off) t += sc[tid - off];
    __syncthreads();
    sc[tid] = t;
    __syncthreads();
  }
  boffs[tid] = sc[tid] - v;           // exclusive block offset
  if (tid == 255) offs[N] = sc[255];  // total edge count
}

extern "C" __global__ __launch_bounds__(256) void k_scan3(const int* __restrict__ deg,
                                                          const int* __restrict__ boffs,
                                                          int* __restrict__ offs, int N) {
  __shared__ int sc[256];
  int tid = threadIdx.x;
  int i = blockIdx.x * 256 + tid;
  int v = (i < N) ? deg[i] : 0;
  sc[tid] = v;
  __syncthreads();
  #pragma unroll
  for (int off = 1; off < 256; off <<= 1) {
    int t = sc[tid];
    if (tid >= off) t += sc[tid - off];
    __syncthreads();
    sc[tid] = t;
    __syncthreads();
  }
  if (i < N) offs[i] = boffs[blockIdx.x] + sc[tid] - v;
}

extern "C" __global__ void k_scatter(const int* __restrict__ src, const int* __restrict__ dst,
                                     const int* __restrict__ offs, int* __restrict__ cursor,
                                     int* __restrict__ csr_src, int E) {
  int e = blockIdx.x * blockDim.x + threadIdx.x;
  if (e < E) {
    int d = dst[e];
    int pos = offs[d] + atomicAdd(&cursor[d], 1);
    csr_src[pos] = src[e];
  }
}

// MFMA transform. Block = 256 thr = 4 waves; block covers 16 nodes x all 8 bt
// (wave w -> bt {2w, 2w+1}). Per wave: W frags in VGPRs (4 f-tiles x 2
// K-steps), A frag per bt/K-step from coalesced-ish fp32 loads (64B segments)
// scaled by rs_out and cvt to fp16. 16 MFMAs/wave. D stored as fp16 (32B
// segments per 16-lane group).
extern "C" __global__ __launch_bounds__(256) void k_transform(
    const float* __restrict__ in_feat, const float* __restrict__ W,
    const float* __restrict__ rs_out, __half* __restrict__ y, int N) {
  int tid = threadIdx.x;
  int wave = tid >> 6, l = tid & 63;
  int col = l & 15;      // A row (node) on load side; D col (f) on store side
  int kg  = l >> 4;      // k-group 0..3
  int n0 = blockIdx.x * 16;

  // Preload W fragments: wf[ft][ks][j] = W[(ks*32 + kg*8 + j)*64 + ft*16 + col]
  half8 wf[4][2];
  #pragma unroll
  for (int ft = 0; ft < 4; ++ft)
    #pragma unroll
    for (int ks = 0; ks < 2; ++ks)
      #pragma unroll
      for (int j = 0; j < 8; ++j)
        wf[ft][ks][j] = (_Float16)W[(ks * 32 + kg * 8 + j) * 64 + ft * 16 + col];

  int nA = n0 + col;
  bool okA = (nA < N);
  float rs = okA ? rs_out[nA] : 0.0f;
  size_t hs = (size_t)4 * (size_t)N;

  #pragma unroll
  for (int p = 0; p < 2; ++p) {
    int bt = wave * 2 + p;
    int b = bt >> 2, t = bt & 3;
    const float* xp = in_feat + (size_t)(b * 256 + t) * (size_t)N + nA;

    float a0f[8], a1f[8];
    #pragma unroll
    for (int j = 0; j < 8; ++j)
      a0f[j] = okA ? xp[(size_t)(kg * 8 + j) * hs] : 0.0f;
    #pragma unroll
    for (int j = 0; j < 8; ++j)
      a1f[j] = okA ? xp[(size_t)(32 + kg * 8 + j) * hs] : 0.0f;

    half8 a0, a1;
    #pragma unroll
    for (int j = 0; j < 8; ++j) {
      a0[j] = (_Float16)(a0f[j] * rs);
      a1[j] = (_Float16)(a1f[j] * rs);
    }

    #pragma unroll
    for (int ft = 0; ft < 4; ++ft) {
      f32x4 acc = {0.f, 0.f, 0.f, 0.f};
      acc = __builtin_amdgcn_mfma_f32_16x16x32_f16(a0, wf[ft][0], acc, 0, 0, 0);
      acc = __builtin_amdgcn_mfma_f32_16x16x32_f16(a1, wf[ft][1], acc, 0, 0, 0);
      // D[row = kg*4 + r][col], row is the node index within the tile
      #pragma unroll
      for (int r = 0; r < 4; ++r) {
        int nr = n0 + kg * 4 + r;
        if (nr < N)
          y[(size_t)nr * 512 + bt * 64 + ft * 16 + col] = __float2half(acc[r]);
      }
    }
  }
}

// Aggregate (R9 exact body — measured best 73.4us): 512 threads = 8 waves;
// wave handles 2 nodes (16-node tile, 33KB LDS -> 4 blocks/CU -> 32 waves/CU).
// Per edge: 2x8B loads (channels 4l..4l+3 and 256+4l..+3), unroll 4.
extern "C" __global__ __launch_bounds__(512) void k_aggregate(
    const __half* __restrict__ y, const int* __restrict__ offs,
    const int* __restrict__ csr_src, const float* __restrict__ rs_in,
    const float* __restrict__ bvec, float* __restrict__ out, int N) {
  __shared__ float agg[16 * 513];
  int tid = threadIdx.x;
  int lane = tid & 63, wave = tid >> 6;   // 8 waves
  int n0 = blockIdx.x * 16;

#define ACC_EDGE(s)                                                          \
  {                                                                          \
    const uint2* rp = (const uint2*)(y + (size_t)(s) * 512);                 \
    uint2 ua = rp[lane];                                                     \
    uint2 ub = rp[64 + lane];                                                \
    float2 f;                                                                \
    f = __half22float2(*(const __half2*)&ua.x); accA.x += f.x; accA.y += f.y;\
    f = __half22float2(*(const __half2*)&ua.y); accA.z += f.x; accA.w += f.y;\
    f = __half22float2(*(const __half2*)&ub.x); accB.x += f.x; accB.y += f.y;\
    f = __half22float2(*(const __half2*)&ub.y); accB.z += f.x; accB.w += f.y;\
  }

  #pragma unroll
  for (int k = 0; k < 2; ++k) {
    int nl = k * 8 + wave;
    int n = n0 + nl;
    float4 accA = {0.f, 0.f, 0.f, 0.f};
    float4 accB = {0.f, 0.f, 0.f, 0.f};
    if (n < N) {
      int j0 = offs[n], j1 = offs[n + 1];
      for (int base = j0; base < j1; base += 64) {
        int idxv = csr_src[base + lane];  // coalesced block of up to 64 indices
        int m = j1 - base; if (m > 64) m = 64;
        int e = 0;
        for (; e + 3 < m; e += 4) {
          int s0 = __builtin_amdgcn_readlane(idxv, e);
          int s1 = __builtin_amdgcn_readlane(idxv, e + 1);
          int s2 = __builtin_amdgcn_readlane(idxv, e + 2);
          int s3 = __builtin_amdgcn_readlane(idxv, e + 3);
          ACC_EDGE(s0); ACC_EDGE(s1); ACC_EDGE(s2); ACC_EDGE(s3);
        }
        for (; e < m; ++e) {
          int s0 = __builtin_amdgcn_readlane(idxv, e);
          ACC_EDGE(s0);
        }
      }
    }
    *(float4*)&agg[nl * 513 + lane * 4] = accA;
    *(float4*)&agg[nl * 513 + 256 + lane * 4] = accB;
  }
#undef ACC_EDGE
  __syncthreads();

  // epilogue: scale, bias, relu, transpose-back to channel-major
  int nl = tid & 15;
  int r0 = tid >> 4;  // 0..31
  int n = n0 + nl;
  float rs = (n < N) ? rs_in[n] : 0.0f;
  #pragma unroll 4
  for (int it = 0; it < 16; ++it) {
    int c = it * 32 + r0;          // c = (b*4+t)*64 + f
    float v = agg[nl * 513 + c];
    int f = c & 63, bt = c >> 6;
    int b = bt >> 2, t = bt & 3;
    v = v * rs + bvec[f];
    v = fmaxf(v, 0.0f);
    if (n < N) out[(size_t)((b * 64 + f) * 4 + t) * (size_t)N + n] = v;
  }
}

extern "C" void kernel_launch(void* const* d_in, const int* in_sizes, int n_in,
                              void* d_out, int out_size, void* d_ws, size_t ws_size,
                              hipStream_t stream) {
  const float* in_feat = (const float*)d_in[0];
  const int*   src     = (const int*)d_in[1];
  const int*   dst     = (const int*)d_in[2];
  const float* W       = (const float*)d_in[3];
  const float* bvec    = (const float*)d_in[4];
  float* out = (float*)d_out;

  int N = in_sizes[0] / 512;   // B*H*T = 2*64*4 = 512
  int E = in_sizes[1];

  int A  = (N + 64) & ~63;     // room for N+1 offsets, 64-aligned
  int EA = (E + 63) & ~63;
  int M  = (N + 255) / 256;    // scan blocks (<= 256 for N <= 65536)

  // layout: the three arrays needing zero-init come first (one memset)
  int*   deg_out_i = (int*)d_ws;        // [A]  zeroed
  int*   deg_in_i  = deg_out_i + A;     // [A]  zeroed
  int*   cursor    = deg_in_i + A;      // [A]  zeroed
  int*   offs      = cursor + A;        // [A] (N+1 used, fully written by scans)
  int*   bsum      = offs + A;          // [256]
  int*   boffs     = bsum + 256;        // [256]
  float* rs_out    = (float*)(boffs + 256);
  float* rs_in     = rs_out + A;
  int*   csr_src   = (int*)(rs_in + A); // [EA] (+slack: y follows, overreads safe)
  __half* y        = (__half*)(csr_src + EA); // [N*512] fp16, plain layout

  hipMemsetAsync(deg_out_i, 0, (size_t)(3 * A) * sizeof(int), stream);
  hipLaunchKernelGGL(k_deg, dim3((E + 255) / 256), dim3(256), 0, stream,
                     src, dst, deg_out_i, deg_in_i, E);
  hipLaunchKernelGGL(k_scan1, dim3(M), dim3(256), 0, stream,
                     deg_in_i, deg_out_i, bsum, rs_out, rs_in, N);
  hipLaunchKernelGGL(k_scan2, dim3(1), dim3(256), 0, stream, bsum, boffs, offs, M, N);
  hipLaunchKernelGGL(k_scan3, dim3(M), dim3(256), 0, stream, deg_in_i, boffs, offs, N);
  hipLaunchKernelGGL(k_scatter, dim3((E + 255) / 256), dim3(256), 0, stream,
                     src, dst, offs, cursor, csr_src, E);
  hipLaunchKernelGGL(k_transform, dim3((N + 15) / 16), dim3(256), 0, stream,
                     in_feat, W, rs_out, y, N);
  hipLaunchKernelGGL(k_aggregate, dim3((N + 15) / 16), dim3(512), 0, stream,
                     y, offs, csr_src, rs_in, bvec, out, N);
}

// Round 16
// 183.592 us; speedup vs baseline: 1.1219x; 1.0025x over previous
//
#include <hip/hip_runtime.h>
#include <hip/hip_fp16.h>

// ---------------------------------------------------------------------------
// GCN layer: out[b][f][t][n] = relu( rsqrt(deg_in[n]) *
//     sum_{e: dst[e]=n} ( rsqrt(deg_out[src[e]]) * x[src[e]] @ W )[b][t][f] + bias[f] )
// Strategy: (1) degrees+CSR, (2) MFMA transform -> y[n][512] fp16 plain
//           node-major, (3) CSR gather-sum + epilogue + transpose-back.
// R16: transform occupancy/ILP fix. R15 shape = 12 waves/CU, no prefetch ->
//      latency-bound at ~65us. Now: 128-thr blocks (2 waves), grid
//      (N/16 x 2 bt-halves) = 6250 blocks -> ~24-32 waves/CU; wave = 2 bt
//      with cross-bt register prefetch (T14 pattern, as in R9's GEMV fix).
//      Fragment mapping m89/m97-verified (R15 absmax-clean): A[l&15][kg*8+j],
//      B[kg*8+j][l&15], D[kg*4+r][l&15]. Aggregate = R9 exact body (73.4us).
// ---------------------------------------------------------------------------

typedef _Float16 half8 __attribute__((ext_vector_type(8)));
typedef float f32x4 __attribute__((ext_vector_type(4)));

extern "C" __global__ void k_deg(const int* __restrict__ src, const int* __restrict__ dst,
                                 int* __restrict__ deg_out, int* __restrict__ deg_in, int E) {
  int e = blockIdx.x * blockDim.x + threadIdx.x;
  if (e < E) {
    atomicAdd(&deg_out[src[e]], 1);
    atomicAdd(&deg_in[dst[e]], 1);
  }
}

// scan1 + rsqrt fused: block sums of deg_in, plus rs arrays.
extern "C" __global__ __launch_bounds__(256) void k_scan1(const int* __restrict__ deg_in,
                                                          const int* __restrict__ deg_out,
                                                          int* __restrict__ bsum,
                                                          float* __restrict__ rs_out,
                                                          float* __restrict__ rs_in, int N) {
  __shared__ int red[256];
  int tid = threadIdx.x;
  int i = blockIdx.x * 256 + tid;
  int di = (i < N) ? deg_in[i] : 0;
  red[tid] = di;
  if (i < N) {
    int a = deg_out[i] > 1 ? deg_out[i] : 1;
    int b = di > 1 ? di : 1;
    rs_out[i] = rsqrtf((float)a);
    rs_in[i]  = rsqrtf((float)b);
  }
  __syncthreads();
  #pragma unroll
  for (int off = 128; off > 0; off >>= 1) {
    if (tid < off) red[tid] += red[tid + off];
    __syncthreads();
  }
  if (tid == 0) bsum[blockIdx.x] = red[0];
}

extern "C" __global__ __launch_bounds__(256) void k_scan2(const int* __restrict__ bsum,
                                                          int* __restrict__ boffs,
                                                          int* __restrict__ offs, int M, int N) {
  __shared__ int sc[256];
  int tid = threadIdx.x;
  int v = (tid < M) ? bsum[tid] : 0;
  sc[tid] = v;
  __syncthreads();
  #pragma unroll
  for (int off = 1; off < 256; off <<= 1) {
    int t = sc[tid];
    if (tid >= off) t += sc[tid - off];
    __syncthreads();
    sc[tid] = t;
    __syncthreads();
  }
  boffs[tid] = sc[tid] - v;           // exclusive block offset
  if (tid == 255) offs[N] = sc[255];  // total edge count
}

extern "C" __global__ __launch_bounds__(256) void k_scan3(const int* __restrict__ deg,
                                                          const int* __restrict__ boffs,
                                                          int* __restrict__ offs, int N) {
  __shared__ int sc[256];
  int tid = threadIdx.x;
  int i = blockIdx.x * 256 + tid;
  int v = (i < N) ? deg[i] : 0;
  sc[tid] = v;
  __syncthreads();
  #pragma unroll
  for (int off = 1; off < 256; off <<= 1) {
    int t = sc[tid];
    if (tid >= off) t += sc[tid - off];
    __syncthreads();
    sc[tid] = t;
    __syncthreads();
  }
  if (i < N) offs[i] = boffs[blockIdx.x] + sc[tid] - v;
}

extern "C" __global__ void k_scatter(const int* __restrict__ src, const int* __restrict__ dst,
                                     const int* __restrict__ offs, int* __restrict__ cursor,
                                     int* __restrict__ csr_src, int E) {
  int e = blockIdx.x * blockDim.x + threadIdx.x;
  if (e < E) {
    int d = dst[e];
    int pos = offs[d] + atomicAdd(&cursor[d], 1);
    csr_src[pos] = src[e];
  }
}

// MFMA transform v3. Block = 128 thr = 2 waves; grid (N/16, 2). Wave w of
// block (blockIdx.y, w) handles bt = blockIdx.y*4 + w*2 + {0,1} for 16 nodes.
// W frags preloaded in VGPRs; A-frags for bt+1 prefetched during bt's MFMAs.
extern "C" __global__ __launch_bounds__(128) void k_transform(
    const float* __restrict__ in_feat, const float* __restrict__ W,
    const float* __restrict__ rs_out, __half* __restrict__ y, int N) {
  int tid = threadIdx.x;
  int wave = tid >> 6, l = tid & 63;
  int col = l & 15;      // A row (node) on load side; D col (f) on store side
  int kg  = l >> 4;      // k-group 0..3
  int n0 = blockIdx.x * 16;
  int btbase = blockIdx.y * 4 + wave * 2;   // bt = btbase, btbase+1

  // Preload W fragments: wf[ft][ks][j] = W[(ks*32 + kg*8 + j)*64 + ft*16 + col]
  half8 wf[4][2];
  #pragma unroll
  for (int ft = 0; ft < 4; ++ft)
    #pragma unroll
    for (int ks = 0; ks < 2; ++ks)
      #pragma unroll
      for (int j = 0; j < 8; ++j)
        wf[ft][ks][j] = (_Float16)W[(ks * 32 + kg * 8 + j) * 64 + ft * 16 + col];

  int nA = n0 + col;
  bool okA = (nA < N);
  float rs = okA ? rs_out[nA] : 0.0f;
  size_t hs = (size_t)4 * (size_t)N;

  float c0[8], c1[8], nx0[8], nx1[8];
  {
    int bt = btbase, b = bt >> 2, t = bt & 3;
    const float* xp = in_feat + (size_t)(b * 256 + t) * (size_t)N + nA;
    #pragma unroll
    for (int j = 0; j < 8; ++j) c0[j] = okA ? xp[(size_t)(kg * 8 + j) * hs] : 0.0f;
    #pragma unroll
    for (int j = 0; j < 8; ++j) c1[j] = okA ? xp[(size_t)(32 + kg * 8 + j) * hs] : 0.0f;
  }

  #pragma unroll
  for (int p = 0; p < 2; ++p) {
    if (p == 0) {  // prefetch bt+1's A-fragments before consuming bt's
      int bt = btbase + 1, b = bt >> 2, t = bt & 3;
      const float* xp = in_feat + (size_t)(b * 256 + t) * (size_t)N + nA;
      #pragma unroll
      for (int j = 0; j < 8; ++j) nx0[j] = okA ? xp[(size_t)(kg * 8 + j) * hs] : 0.0f;
      #pragma unroll
      for (int j = 0; j < 8; ++j) nx1[j] = okA ? xp[(size_t)(32 + kg * 8 + j) * hs] : 0.0f;
    }
    int bt = btbase + p;

    half8 a0, a1;
    #pragma unroll
    for (int j = 0; j < 8; ++j) {
      a0[j] = (_Float16)(c0[j] * rs);
      a1[j] = (_Float16)(c1[j] * rs);
    }

    #pragma unroll
    for (int ft = 0; ft < 4; ++ft) {
      f32x4 acc = {0.f, 0.f, 0.f, 0.f};
      acc = __builtin_amdgcn_mfma_f32_16x16x32_f16(a0, wf[ft][0], acc, 0, 0, 0);
      acc = __builtin_amdgcn_mfma_f32_16x16x32_f16(a1, wf[ft][1], acc, 0, 0, 0);
      #pragma unroll
      for (int r = 0; r < 4; ++r) {
        int nr = n0 + kg * 4 + r;
        if (nr < N)
          y[(size_t)nr * 512 + bt * 64 + ft * 16 + col] = __float2half(acc[r]);
      }
    }

    if (p == 0) {
      #pragma unroll
      for (int j = 0; j < 8; ++j) { c0[j] = nx0[j]; c1[j] = nx1[j]; }
    }
  }
}

// Aggregate (R9 exact body — measured best 73.4us): 512 threads = 8 waves;
// wave handles 2 nodes (16-node tile, 33KB LDS -> 4 blocks/CU -> 32 waves/CU).
// Per edge: 2x8B loads (channels 4l..4l+3 and 256+4l..+3), unroll 4.
extern "C" __global__ __launch_bounds__(512) void k_aggregate(
    const __half* __restrict__ y, const int* __restrict__ offs,
    const int* __restrict__ csr_src, const float* __restrict__ rs_in,
    const float* __restrict__ bvec, float* __restrict__ out, int N) {
  __shared__ float agg[16 * 513];
  int tid = threadIdx.x;
  int lane = tid & 63, wave = tid >> 6;   // 8 waves
  int n0 = blockIdx.x * 16;

#define ACC_EDGE(s)                                                          \
  {                                                                          \
    const uint2* rp = (const uint2*)(y + (size_t)(s) * 512);                 \
    uint2 ua = rp[lane];                                                     \
    uint2 ub = rp[64 + lane];                                                \
    float2 f;                                                                \
    f = __half22float2(*(const __half2*)&ua.x); accA.x += f.x; accA.y += f.y;\
    f = __half22float2(*(const __half2*)&ua.y); accA.z += f.x; accA.w += f.y;\
    f = __half22float2(*(const __half2*)&ub.x); accB.x += f.x; accB.y += f.y;\
    f = __half22float2(*(const __half2*)&ub.y); accB.z += f.x; accB.w += f.y;\
  }

  #pragma unroll
  for (int k = 0; k < 2; ++k) {
    int nl = k * 8 + wave;
    int n = n0 + nl;
    float4 accA = {0.f, 0.f, 0.f, 0.f};
    float4 accB = {0.f, 0.f, 0.f, 0.f};
    if (n < N) {
      int j0 = offs[n], j1 = offs[n + 1];
      for (int base = j0; base < j1; base += 64) {
        int idxv = csr_src[base + lane];  // coalesced block of up to 64 indices
        int m = j1 - base; if (m > 64) m = 64;
        int e = 0;
        for (; e + 3 < m; e += 4) {
          int s0 = __builtin_amdgcn_readlane(idxv, e);
          int s1 = __builtin_amdgcn_readlane(idxv, e + 1);
          int s2 = __builtin_amdgcn_readlane(idxv, e + 2);
          int s3 = __builtin_amdgcn_readlane(idxv, e + 3);
          ACC_EDGE(s0); ACC_EDGE(s1); ACC_EDGE(s2); ACC_EDGE(s3);
        }
        for (; e < m; ++e) {
          int s0 = __builtin_amdgcn_readlane(idxv, e);
          ACC_EDGE(s0);
        }
      }
    }
    *(float4*)&agg[nl * 513 + lane * 4] = accA;
    *(float4*)&agg[nl * 513 + 256 + lane * 4] = accB;
  }
#undef ACC_EDGE
  __syncthreads();

  // epilogue: scale, bias, relu, transpose-back to channel-major
  int nl = tid & 15;
  int r0 = tid >> 4;  // 0..31
  int n = n0 + nl;
  float rs = (n < N) ? rs_in[n] : 0.0f;
  #pragma unroll 4
  for (int it = 0; it < 16; ++it) {
    int c = it * 32 + r0;          // c = (b*4+t)*64 + f
    float v = agg[nl * 513 + c];
    int f = c & 63, bt = c >> 6;
    int b = bt >> 2, t = bt & 3;
    v = v * rs + bvec[f];
    v = fmaxf(v, 0.0f);
    if (n < N) out[(size_t)((b * 64 + f) * 4 + t) * (size_t)N + n] = v;
  }
}

extern "C" void kernel_launch(void* const* d_in, const int* in_sizes, int n_in,
                              void* d_out, int out_size, void* d_ws, size_t ws_size,
                              hipStream_t stream) {
  const float* in_feat = (const float*)d_in[0];
  const int*   src     = (const int*)d_in[1];
  const int*   dst     = (const int*)d_in[2];
  const float* W       = (const float*)d_in[3];
  const float* bvec    = (const float*)d_in[4];
  float* out = (float*)d_out;

  int N = in_sizes[0] / 512;   // B*H*T = 2*64*4 = 512
  int E = in_sizes[1];

  int A  = (N + 64) & ~63;     // room for N+1 offsets, 64-aligned
  int EA = (E + 63) & ~63;
  int M  = (N + 255) / 256;    // scan blocks (<= 256 for N <= 65536)

  // layout: the three arrays needing zero-init come first (one memset)
  int*   deg_out_i = (int*)d_ws;        // [A]  zeroed
  int*   deg_in_i  = deg_out_i + A;     // [A]  zeroed
  int*   cursor    = deg_in_i + A;      // [A]  zeroed
  int*   offs      = cursor + A;        // [A] (N+1 used, fully written by scans)
  int*   bsum      = offs + A;          // [256]
  int*   boffs     = bsum + 256;        // [256]
  float* rs_out    = (float*)(boffs + 256);
  float* rs_in     = rs_out + A;
  int*   csr_src   = (int*)(rs_in + A); // [EA] (+slack: y follows, overreads safe)
  __half* y        = (__half*)(csr_src + EA); // [N*512] fp16, plain layout

  hipMemsetAsync(deg_out_i, 0, (size_t)(3 * A) * sizeof(int), stream);
  hipLaunchKernelGGL(k_deg, dim3((E + 255) / 256), dim3(256), 0, stream,
                     src, dst, deg_out_i, deg_in_i, E);
  hipLaunchKernelGGL(k_scan1, dim3(M), dim3(256), 0, stream,
                     deg_in_i, deg_out_i, bsum, rs_out, rs_in, N);
  hipLaunchKernelGGL(k_scan2, dim3(1), dim3(256), 0, stream, bsum, boffs, offs, M, N);
  hipLaunchKernelGGL(k_scan3, dim3(M), dim3(256), 0, stream, deg_in_i, boffs, offs, N);
  hipLaunchKernelGGL(k_scatter, dim3((E + 255) / 256), dim3(256), 0, stream,
                     src, dst, offs, cursor, csr_src, E);
  hipLaunchKernelGGL(k_transform, dim3((N + 15) / 16, 2), dim3(128), 0, stream,
                     in_feat, W, rs_out, y, N);
  hipLaunchKernelGGL(k_aggregate, dim3((N + 15) / 16), dim3(512), 0, stream,
                     y, offs, csr_src, rs_in, bvec, out, N);
}